// Round 16
// baseline (158.951 us; speedup 1.0000x reference)
//
#include <hip/hip_runtime.h>

#define GS3 2097152          // 128^3
#define NS1 262144           // 64^3
#define NS2 32768            // 32^3
#define NS3 4096             // 16^3
#define NS4 512              // 8^3
#define NS5 64               // 4^3

// Output element offsets (float index) for each scale's block of [Ss^3, 12]
#define OB1 25165824
#define OB2 28311552
#define OB3 28704768
#define OB4 28753920
#define OB5 28760064

#define NREG 512             // regions: x-pair (x>>1, 6b) * y-16th (y>>4, 3b)
#define RVOX 4096            // voxels per region: 2(x) * 16(y) * 128(z) = 16KB LDS
#define PPB  8192            // points per binning block
#define RPT  (PPB / 256)     // records per thread (register-staged)
#define CAPB 64              // per-(block,region) slot capacity (mean 16, P(>64)~1e-17)

// out_kernel thread-space: scale0 | scale1 | scale2 | scale3 | scale4(waves) | scale5(waves)
#define T1 (GS3)
#define T2 (T1 + NS1)
#define T3 (T2 + NS2)
#define T4 (T3 + NS3)
#define T5 (T4 + NS4 * 64)
#define TEND (T5 + NS5 * 64)   // 2,433,024 = 9504 * 256

// Record: (region<<18) | (localvoxel<<6) | label
//   region   = (x>>1)<<3 | (y>>4)             (9 bits)
//   localvox = (x&1)<<11 | (y&15)<<7 | z      (12 bits)
//   label    = instance+1                     (6 bits, 1..50)

// ---------------------------------------------------------------------------
// 1a) Binning with block-local counting sort. Raw records in registers;
//     sorted runs written to FIXED per-(block,region) 256B slots -> no global
//     atomics anywhere, no counter zeroing, fully deterministic.
// ---------------------------------------------------------------------------
__global__ __launch_bounds__(256) void bin_kernel(
    const int* __restrict__ coords, const float* __restrict__ inst,
    unsigned int* __restrict__ counts, unsigned int* __restrict__ bins, int N) {
  __shared__ unsigned srec[PPB];     // 32 KB region-sorted records
  __shared__ unsigned hist[NREG];    // 2 KB: counts, then scatter cursor
  __shared__ unsigned lofs[NREG];    // 2 KB: block-local region starts
  __shared__ unsigned part[256];     // 1 KB: scan workspace
  __shared__ unsigned total_sh;
  unsigned vrec[RPT];                // register-staged raw records
  int tid = threadIdx.x;
  int bid = blockIdx.x;
  int start = bid * PPB;
  for (int j = tid; j < NREG; j += 256) hist[j] = 0;
  __syncthreads();
  // phase 1: read points, build records in registers, count per region
#pragma unroll
  for (int j = 0; j < RPT; j++) {
    int i = start + j * 256 + tid;
    unsigned v = 0xFFFFFFFFu;
    if (i < N) {
      int x = coords[3 * i + 0];
      int y = coords[3 * i + 1];
      int z = coords[3 * i + 2];
      unsigned lab = (unsigned)inst[i] + 1u;                          // 1..50
      unsigned r = (((unsigned)x >> 1) << 3) | ((unsigned)y >> 4);    // 9 bits
      unsigned l = (((unsigned)x & 1) << 11) | (((unsigned)y & 15) << 7) | (unsigned)z;
      v = (r << 18) | (l << 6) | lab;
      atomicAdd(&hist[r], 1u);
    }
    vrec[j] = v;
  }
  __syncthreads();
  // phase 2a: exclusive scan of hist[512] -> lofs (2 entries/thread);
  //           also store per-region counts (clamped) to global, non-atomic
  unsigned ha = hist[2 * tid], hb = hist[2 * tid + 1];
  counts[(size_t)bid * NREG + 2 * tid]     = ha < CAPB ? ha : CAPB;
  counts[(size_t)bid * NREG + 2 * tid + 1] = hb < CAPB ? hb : CAPB;
  part[tid] = ha + hb;
  __syncthreads();
  for (int o = 1; o < 256; o <<= 1) {
    unsigned v = part[tid];
    unsigned add = (tid >= o) ? part[tid - o] : 0u;
    __syncthreads();
    part[tid] = v + add;
    __syncthreads();
  }
  unsigned inc = part[tid];
  unsigned ex = inc - (ha + hb);
  lofs[2 * tid] = ex;
  lofs[2 * tid + 1] = ex + ha;
  if (tid == 255) total_sh = inc;
  __syncthreads();
  for (int j = tid; j < NREG; j += 256) hist[j] = 0;   // reuse as cursor
  __syncthreads();
  // phase 3a: scatter records from registers into region-sorted LDS buffer
#pragma unroll
  for (int j = 0; j < RPT; j++) {
    unsigned v = vrec[j];
    if (v != 0xFFFFFFFFu) {
      unsigned r = v >> 18;
      unsigned pos = lofs[r] + atomicAdd(&hist[r], 1u);
      srec[pos] = v;
    }
  }
  __syncthreads();
  // phase 3b: write sorted runs to fixed 256B-aligned slots (coalesced)
  unsigned total = total_sh;
  size_t bbase = (size_t)bid * NREG * CAPB;
  for (unsigned j = tid; j < total; j += 256) {
    unsigned v = srec[j];
    unsigned r = v >> 18;
    unsigned p = j - lofs[r];                 // position within region run
    if (p < CAPB) bins[bbase + r * CAPB + p] = v & 0x3FFFFu;
  }
}

// ---------------------------------------------------------------------------
// 1b+2) Build P for one region in LDS (gathering the per-block slots) and
//     pool its coarse cells (fused pool1).
//     Region r: x in {2X,2X+1} (X=r>>3), y in [yo*16,yo*16+16) (yo=r&7).
// ---------------------------------------------------------------------------
__global__ __launch_bounds__(256) void build_pool_kernel(
    const unsigned int* __restrict__ counts, const unsigned int* __restrict__ bins,
    unsigned int* __restrict__ P,
    double* __restrict__ vs1, double* __restrict__ as1, int nchunks) {
  __shared__ unsigned grid[RVOX];    // 16 KB
  int r = blockIdx.x;
  int tid = threadIdx.x;
  for (int j = tid; j < RVOX; j += 256) grid[j] = 0;
  __syncthreads();
  for (int b = tid; b < nchunks; b += 256) {
    int cb = (int)counts[(size_t)b * NREG + r];
    const unsigned* src = bins + ((size_t)b * NREG + r) * CAPB;
    for (int k = 0; k < cb; k++) {
      unsigned v = src[k];
      atomicAdd(&grid[v >> 6], (1u << 20) | (v & 63u));
    }
  }
  __syncthreads();
  int X = r >> 3, yo = r & 7;        // x-pair index, y-16th index
  // write P: for each dx, a contiguous 8KB span (16y * 128z dwords)
  unsigned pbase = ((unsigned)(2 * X) << 14) | ((unsigned)yo << 11);
  for (int j = tid; j < RVOX; j += 256) {
    // j = (x&1)<<11 | (y&15)<<7 | z
    P[pbase + ((j >> 11) << 14) + (j & 0x7FF)] = grid[j];
  }
  // fused pool1: 512 coarse cells (1 X-plane, 8 coarse y, 64 coarse z)
  for (int c = tid; c < 512; c += 256) {
    int yl = c >> 6, Z = c & 63;
    double vs = 0.0, as = 0.0;
#pragma unroll
    for (int dx = 0; dx < 2; dx++)
#pragma unroll
      for (int dy = 0; dy < 2; dy++)
#pragma unroll
        for (int dz = 0; dz < 2; dz++) {
          int j = (dx << 11) | ((2 * yl + dy) << 7) | (2 * Z + dz);
          unsigned pk = grid[j];
          unsigned cc = pk >> 20;
          if (cc) {
            vs += (double)(pk & 0xFFFFFu) / (double)cc;
            as += 1.0;
          }
        }
    int q = (X << 12) | (((yo << 3) + yl) << 6) | Z;
    vs1[q] = vs;
    as1[q] = as;
  }
}

// ---------------------------------------------------------------------------
// Helpers for the fused output kernel.
// ---------------------------------------------------------------------------
__device__ __forceinline__ void writeOut12(float* dst, const float* f, const float* m) {
  float4 r0 = {f[0], f[1], f[2], f[3]};
  float4 r1 = {f[4], f[5], m[0], m[1]};
  float4 r2 = {m[2], m[3], m[4], m[5]};
  float4* o = (float4*)dst;
  o[0] = r0; o[1] = r1; o[2] = r2;
}

// Per-thread coarse output (scales 2,3): sum own+6 neighbor cells from vs1.
__device__ __forceinline__ void coarse_thread(
    const double* __restrict__ vs1, const double* __restrict__ as1,
    float* __restrict__ out, int q, int lg, int lc, long long obase) {
  int G = 1 << lg, C = 1 << lc;
  int X = q >> (2 * lg), Y = (q >> lg) & (G - 1), Z = q & (G - 1);
  const int cx[7] = {X, X - 1, X + 1, X, X, X, X};
  const int cy[7] = {Y, Y, Y, Y - 1, Y + 1, Y, Y};
  const int cz[7] = {Z, Z, Z, Z, Z, Z - 1, Z + 1};
  double vsum[7], asum[7];
#pragma unroll
  for (int c = 0; c < 7; c++) {
    vsum[c] = 0.0; asum[c] = 0.0;
    if (cx[c] < 0 || cx[c] >= G || cy[c] < 0 || cy[c] >= G || cz[c] < 0 || cz[c] >= G)
      continue;
    int bx = cx[c] << lc, by = cy[c] << lc, bz = cz[c] << lc;
    for (int dx = 0; dx < C; dx++)
      for (int dy = 0; dy < C; dy++)
        for (int dz = 0; dz < C; dz++) {
          int p1 = ((bx + dx) << 12) | ((by + dy) << 6) | (bz + dz);
          vsum[c] += vs1[p1];
          asum[c] += as1[p1];
        }
  }
  float f[6], m[6];
  if (asum[0] > 0.0) {
    double vc = vsum[0] / asum[0];
#pragma unroll
    for (int k = 0; k < 6; k++) {
      double van = (asum[k + 1] > 0.0) ? vsum[k + 1] / asum[k + 1] : 0.0;
      f[k] = (fabs(van - vc) < 0.01) ? 1.f : 0.f;
      m[k] = (van > 0.0) ? 1.f : 0.f;
    }
  } else {
#pragma unroll
    for (int k = 0; k < 6; k++) { f[k] = 0.f; m[k] = 0.f; }
  }
  writeOut12(out + obase + 12ll * q, f, m);
}

// Per-wave coarse output (scales 4,5): lanes split children, butterfly reduce.
__device__ __forceinline__ void coarse_wave(
    const double* __restrict__ vs1, const double* __restrict__ as1,
    float* __restrict__ out, int t, int lg, int lc, long long obase) {
  int w = t >> 6, lane = t & 63;
  int G = 1 << lg, C = 1 << lc, vol = C * C * C;
  int X = w >> (2 * lg), Y = (w >> lg) & (G - 1), Z = w & (G - 1);
  const int cx[7] = {X, X - 1, X + 1, X, X, X, X};
  const int cy[7] = {Y, Y, Y, Y - 1, Y + 1, Y, Y};
  const int cz[7] = {Z, Z, Z, Z, Z, Z - 1, Z + 1};
  double vsum[7], asum[7];
#pragma unroll
  for (int c = 0; c < 7; c++) {
    vsum[c] = 0.0; asum[c] = 0.0;
    if (cx[c] < 0 || cx[c] >= G || cy[c] < 0 || cy[c] >= G || cz[c] < 0 || cz[c] >= G)
      continue;
    int bx = cx[c] << lc, by = cy[c] << lc, bz = cz[c] << lc;
    for (int ch = lane; ch < vol; ch += 64) {
      int dx = ch >> (2 * lc), dy = (ch >> lc) & (C - 1), dz = ch & (C - 1);
      int p1 = ((bx + dx) << 12) | ((by + dy) << 6) | (bz + dz);
      vsum[c] += vs1[p1];
      asum[c] += as1[p1];
    }
  }
#pragma unroll
  for (int c = 0; c < 7; c++) {
    for (int o = 32; o > 0; o >>= 1) {
      vsum[c] += __shfl_down(vsum[c], o, 64);
      asum[c] += __shfl_down(asum[c], o, 64);
    }
  }
  if (lane == 0) {
    float f[6], m[6];
    if (asum[0] > 0.0) {
      double vc = vsum[0] / asum[0];
#pragma unroll
      for (int k = 0; k < 6; k++) {
        double van = (asum[k + 1] > 0.0) ? vsum[k + 1] / asum[k + 1] : 0.0;
        f[k] = (fabs(van - vc) < 0.01) ? 1.f : 0.f;
        m[k] = (van > 0.0) ? 1.f : 0.f;
      }
    } else {
#pragma unroll
      for (int k = 0; k < 6; k++) { f[k] = 0.f; m[k] = 0.f; }
    }
    writeOut12(out + obase + 12ll * w, f, m);
  }
}

// ---------------------------------------------------------------------------
// 3) Fused output kernel: scale-0 (exact int), scale-1 (vs1 direct),
//    scales 2-5 recomputed from vs1 (poolRest folded in; one fewer dispatch).
// ---------------------------------------------------------------------------
__global__ __launch_bounds__(256) void out_kernel(
    const unsigned int* __restrict__ P,
    const double* __restrict__ vs1, const double* __restrict__ as1,
    float* __restrict__ out) {
  int p = blockIdx.x * blockDim.x + threadIdx.x;
  if (p < GS3) {
    unsigned pk = P[p];
    int cc = (int)(pk >> 20);
    float4 r0 = {0.f, 0.f, 0.f, 0.f}, r1 = r0, r2 = r0;
    if (cc) {
      int sc = (int)(pk & 0xFFFFFu);
      int x = p >> 14, y = (p >> 7) & 127, z = p & 127;
      const int off[6] = {-(1 << 14), (1 << 14), -(1 << 7), (1 << 7), -1, 1};
      const bool inb[6] = {x > 0, x < 127, y > 0, y < 127, z > 0, z < 127};
      float f[6], m[6];
#pragma unroll
      for (int k = 0; k < 6; k++) {
        int sn = 0, cn = 0;
        if (inb[k]) {
          unsigned pn = P[p + off[k]];
          cn = (int)(pn >> 20);
          sn = (int)(pn & 0xFFFFFu);
        }
        if (cn) {
          long long d = (long long)sn * cc - (long long)sc * cn;
          if (d < 0) d = -d;
          f[k] = (100ll * d < (long long)cn * cc) ? 1.f : 0.f;
          m[k] = 1.f;
        } else {
          f[k] = 0.f;                          // vc >= 1 so |0-vc| >= 1
          m[k] = 0.f;
        }
      }
      r0 = {f[0], f[1], f[2], f[3]};
      r1 = {f[4], f[5], m[0], m[1]};
      r2 = {m[2], m[3], m[4], m[5]};
    }
    float4* o = (float4*)(out + 12ll * p);
    o[0] = r0; o[1] = r1; o[2] = r2;
    return;
  }
  if (p < T2) {                       // scale 1: direct vs1 neighbors
    int q = p - T1;
    int X = q >> 12, Y = (q >> 6) & 63, Z = q & 63;
    double ac = as1[q];
    float f[6], m[6];
    if (ac > 0.0) {
      double vc = vs1[q] / ac;
      const int off[6] = {-4096, 4096, -64, 64, -1, 1};
      const bool inb[6] = {X > 0, X < 63, Y > 0, Y < 63, Z > 0, Z < 63};
#pragma unroll
      for (int k = 0; k < 6; k++) {
        double van = 0.0;
        if (inb[k]) {
          double an = as1[q + off[k]];
          if (an > 0.0) van = vs1[q + off[k]] / an;
        }
        f[k] = (fabs(van - vc) < 0.01) ? 1.f : 0.f;
        m[k] = (van > 0.0) ? 1.f : 0.f;
      }
    } else {
#pragma unroll
      for (int k = 0; k < 6; k++) { f[k] = 0.f; m[k] = 0.f; }
    }
    writeOut12(out + OB1 + 12ll * q, f, m);
    return;
  }
  if (p < T3) { coarse_thread(vs1, as1, out, p - T2, 5, 1, OB2); return; }
  if (p < T4) { coarse_thread(vs1, as1, out, p - T3, 4, 2, OB3); return; }
  if (p < T5) { coarse_wave(vs1, as1, out, p - T4, 3, 3, OB4); return; }
  if (p < TEND) { coarse_wave(vs1, as1, out, p - T5, 2, 4, OB5); }
}

// ---------------------------------------------------------------------------
extern "C" void kernel_launch(void* const* d_in, const int* in_sizes, int n_in,
                              void* d_out, int out_size, void* d_ws, size_t ws_size,
                              hipStream_t stream) {
  const int* coords = (const int*)d_in[0];
  const float* inst = (const float*)d_in[1];
  int N = in_sizes[1];            // 4,000,000 points
  float* out = (float*)d_out;
  int nchunks = (N + PPB - 1) / PPB;                     // 489

  // workspace layout
  char* base = (char*)d_ws;
  unsigned int* P = (unsigned int*)base;                 // 8 MB
  double* vs1 = (double*)(base + 8388608);               // 2 MB
  double* as1 = vs1 + NS1;                               // 2 MB
  size_t counts_off = 13182976;                          // 1KB-aligned
  unsigned int* counts = (unsigned int*)(base + counts_off);
  size_t bins_off = counts_off + ((size_t)nchunks * NREG * 4 + 1023) / 1024 * 1024;
  unsigned int* bins = (unsigned int*)(base + bins_off);
  size_t need = bins_off + (size_t)nchunks * NREG * CAPB * 4;  // ~78.4 MB
  if (ws_size < need) return;  // never happens at this problem size

  bin_kernel<<<nchunks, 256, 0, stream>>>(coords, inst, counts, bins, N);
  build_pool_kernel<<<NREG, 256, 0, stream>>>(counts, bins, P, vs1, as1, nchunks);
  out_kernel<<<TEND / 256, 256, 0, stream>>>(P, vs1, as1, out);
}

// Round 17
// 92.527 us; speedup vs baseline: 1.7179x; 1.7179x over previous
//
#include <hip/hip_runtime.h>

#define GS3 2097152          // 128^3
#define NS1 262144           // 64^3
#define NS2 32768            // 32^3
#define NS3 4096             // 16^3
#define NS4 512              // 8^3
#define NS5 64               // 4^3
#define NSALL 299584         // NS1+NS2+NS3+NS4+NS5

// Output element offsets (float index) for each scale's block of [Ss^3, 12]
#define OB1 25165824
#define OB2 28311552
#define OB3 28704768
#define OB4 28753920
#define OB5 28760064

#define NREG 512             // regions: x-pair (x>>1, 6b) * y-16th (y>>4, 3b)
#define RVOX 4096            // voxels per region: 2(x) * 16(y) * 128(z) = 16KB LDS
#define PPB  8192            // points per binning block
#define RPT  (PPB / 256)     // records per thread (register-staged)
#define CAPB 64              // per-(block,region) slot capacity (mean 16, P(>64)~1e-17)

#define H0   (GS3 / 2)       // scale-0 voxel-pair threads
#define TEND (H0 + NSALL)    // out_kernel total threads

// Record: (region<<18) | (localvoxel<<6) | label
//   region   = (x>>1)<<3 | (y>>4)             (9 bits)
//   localvox = (x&1)<<11 | (y&15)<<7 | z      (12 bits)
//   label    = instance+1                     (6 bits, 1..50)

// ---------------------------------------------------------------------------
// 1a) Binning with block-local counting sort. Raw records in registers;
//     sorted runs written to FIXED per-(block,region) 256B slots -> no global
//     atomics anywhere, no counter zeroing, fully deterministic.
// ---------------------------------------------------------------------------
__global__ __launch_bounds__(256) void bin_kernel(
    const int* __restrict__ coords, const float* __restrict__ inst,
    unsigned int* __restrict__ counts, unsigned int* __restrict__ bins, int N) {
  __shared__ unsigned srec[PPB];     // 32 KB region-sorted records
  __shared__ unsigned hist[NREG];    // 2 KB: counts, then scatter cursor
  __shared__ unsigned lofs[NREG];    // 2 KB: block-local region starts
  __shared__ unsigned part[256];     // 1 KB: scan workspace
  __shared__ unsigned total_sh;
  unsigned vrec[RPT];                // register-staged raw records
  int tid = threadIdx.x;
  int bid = blockIdx.x;
  int start = bid * PPB;
  for (int j = tid; j < NREG; j += 256) hist[j] = 0;
  __syncthreads();
  // phase 1: read points, build records in registers, count per region
#pragma unroll
  for (int j = 0; j < RPT; j++) {
    int i = start + j * 256 + tid;
    unsigned v = 0xFFFFFFFFu;
    if (i < N) {
      int x = coords[3 * i + 0];
      int y = coords[3 * i + 1];
      int z = coords[3 * i + 2];
      unsigned lab = (unsigned)inst[i] + 1u;                          // 1..50
      unsigned r = (((unsigned)x >> 1) << 3) | ((unsigned)y >> 4);    // 9 bits
      unsigned l = (((unsigned)x & 1) << 11) | (((unsigned)y & 15) << 7) | (unsigned)z;
      v = (r << 18) | (l << 6) | lab;
      atomicAdd(&hist[r], 1u);
    }
    vrec[j] = v;
  }
  __syncthreads();
  // phase 2a: exclusive scan of hist[512] -> lofs (2 entries/thread);
  //           also store per-region counts (clamped) to global, non-atomic
  unsigned ha = hist[2 * tid], hb = hist[2 * tid + 1];
  counts[(size_t)bid * NREG + 2 * tid]     = ha < CAPB ? ha : CAPB;
  counts[(size_t)bid * NREG + 2 * tid + 1] = hb < CAPB ? hb : CAPB;
  part[tid] = ha + hb;
  __syncthreads();
  for (int o = 1; o < 256; o <<= 1) {
    unsigned v = part[tid];
    unsigned add = (tid >= o) ? part[tid - o] : 0u;
    __syncthreads();
    part[tid] = v + add;
    __syncthreads();
  }
  unsigned inc = part[tid];
  unsigned ex = inc - (ha + hb);
  lofs[2 * tid] = ex;
  lofs[2 * tid + 1] = ex + ha;
  if (tid == 255) total_sh = inc;
  __syncthreads();
  for (int j = tid; j < NREG; j += 256) hist[j] = 0;   // reuse as cursor
  __syncthreads();
  // phase 3a: scatter records from registers into region-sorted LDS buffer
#pragma unroll
  for (int j = 0; j < RPT; j++) {
    unsigned v = vrec[j];
    if (v != 0xFFFFFFFFu) {
      unsigned r = v >> 18;
      unsigned pos = lofs[r] + atomicAdd(&hist[r], 1u);
      srec[pos] = v;
    }
  }
  __syncthreads();
  // phase 3b: write sorted runs to fixed 256B-aligned slots (coalesced)
  unsigned total = total_sh;
  size_t bbase = (size_t)bid * NREG * CAPB;
  for (unsigned j = tid; j < total; j += 256) {
    unsigned v = srec[j];
    unsigned r = v >> 18;
    unsigned p = j - lofs[r];                 // position within region run
    if (p < CAPB) bins[bbase + r * CAPB + p] = v & 0x3FFFFu;
  }
}

// ---------------------------------------------------------------------------
// 1b+2) Build P for one region in LDS (gathering the per-block slots) and
//     pool its coarse cells (fused pool1).
//     Region r: x in {2X,2X+1} (X=r>>3), y in [yo*16,yo*16+16) (yo=r&7).
// ---------------------------------------------------------------------------
__global__ __launch_bounds__(256) void build_pool_kernel(
    const unsigned int* __restrict__ counts, const unsigned int* __restrict__ bins,
    unsigned int* __restrict__ P,
    double* __restrict__ vs1, double* __restrict__ as1, int nchunks) {
  __shared__ unsigned grid[RVOX];    // 16 KB
  int r = blockIdx.x;
  int tid = threadIdx.x;
  for (int j = tid; j < RVOX; j += 256) grid[j] = 0;
  __syncthreads();
  for (int b = tid; b < nchunks; b += 256) {
    int cb = (int)counts[(size_t)b * NREG + r];
    const unsigned* src = bins + ((size_t)b * NREG + r) * CAPB;
    for (int k = 0; k < cb; k++) {
      unsigned v = src[k];
      atomicAdd(&grid[v >> 6], (1u << 20) | (v & 63u));
    }
  }
  __syncthreads();
  int X = r >> 3, yo = r & 7;        // x-pair index, y-16th index
  // write P: for each dx, a contiguous 8KB span (16y * 128z dwords)
  unsigned pbase = ((unsigned)(2 * X) << 14) | ((unsigned)yo << 11);
  for (int j = tid; j < RVOX; j += 256) {
    // j = (x&1)<<11 | (y&15)<<7 | z
    P[pbase + ((j >> 11) << 14) + (j & 0x7FF)] = grid[j];
  }
  // fused pool1: 512 coarse cells (1 X-plane, 8 coarse y, 64 coarse z)
  for (int c = tid; c < 512; c += 256) {
    int yl = c >> 6, Z = c & 63;
    double vs = 0.0, as = 0.0;
#pragma unroll
    for (int dx = 0; dx < 2; dx++)
#pragma unroll
      for (int dy = 0; dy < 2; dy++)
#pragma unroll
        for (int dz = 0; dz < 2; dz++) {
          int j = (dx << 11) | ((2 * yl + dy) << 7) | (2 * Z + dz);
          unsigned pk = grid[j];
          unsigned cc = pk >> 20;
          if (cc) {
            vs += (double)(pk & 0xFFFFFu) / (double)cc;
            as += 1.0;
          }
        }
    int q = (X << 12) | (((yo << 3) + yl) << 6) | Z;
    vs1[q] = vs;
    as1[q] = as;
  }
}

// ---------------------------------------------------------------------------
// 3) Pool scales 2..5 from scale-1 sums (sums are additive) — R14-proven.
// ---------------------------------------------------------------------------
__global__ __launch_bounds__(256) void poolRest_kernel(
    const double* __restrict__ vs1, const double* __restrict__ as1,
    double* __restrict__ vs2, double* __restrict__ as2,
    double* __restrict__ vs3, double* __restrict__ as3,
    double* __restrict__ vs4, double* __restrict__ as4,
    double* __restrict__ vs5, double* __restrict__ as5) {
  int t = blockIdx.x * blockDim.x + threadIdx.x;

  if (t < NS2) {
    int q = t;
    int X = q >> 10, Y = (q >> 5) & 31, Z = q & 31;
    double vs = 0.0, as = 0.0;
#pragma unroll
    for (int dx = 0; dx < 2; dx++)
#pragma unroll
      for (int dy = 0; dy < 2; dy++)
#pragma unroll
        for (int dz = 0; dz < 2; dz++) {
          int p = ((((X << 1) + dx) << 12) + (((Y << 1) + dy) << 6) + ((Z << 1) + dz));
          vs += vs1[p];
          as += as1[p];
        }
    vs2[q] = vs;
    as2[q] = as;
    return;
  }
  t -= NS2;
  if (t < NS3) {
    int q = t;
    int X = q >> 8, Y = (q >> 4) & 15, Z = q & 15;
    double vs = 0.0, as = 0.0;
    for (int dx = 0; dx < 4; dx++)
      for (int dy = 0; dy < 4; dy++)
#pragma unroll
        for (int dz = 0; dz < 4; dz++) {
          int p = ((((X << 2) + dx) << 12) + (((Y << 2) + dy) << 6) + ((Z << 2) + dz));
          vs += vs1[p];
          as += as1[p];
        }
    vs3[q] = vs;
    as3[q] = as;
    return;
  }
  t -= NS3;
  if (t < NS4 * 64) {
    int w = t >> 6, lane = t & 63;
    int X = w >> 6, Y = (w >> 3) & 7, Z = w & 7;
    double vs = 0.0, as = 0.0;
#pragma unroll
    for (int j = 0; j < 8; j++) {
      int c = lane * 8 + j;
      int dx = c >> 6, dy = (c >> 3) & 7, dz = c & 7;
      int p = ((((X << 3) + dx) << 12) + (((Y << 3) + dy) << 6) + ((Z << 3) + dz));
      vs += vs1[p];
      as += as1[p];
    }
    for (int o = 32; o > 0; o >>= 1) {
      vs += __shfl_down(vs, o, 64);
      as += __shfl_down(as, o, 64);
    }
    if (lane == 0) { vs4[w] = vs; as4[w] = as; }
    return;
  }
  t -= NS4 * 64;
  if (t < NS5 * 64) {
    int w = t >> 6, lane = t & 63;
    int X = w >> 4, Y = (w >> 2) & 3, Z = w & 3;
    double vs = 0.0, as = 0.0;
    for (int j = 0; j < 64; j++) {
      int c = lane * 64 + j;
      int dx = c >> 8, dy = (c >> 4) & 15, dz = c & 15;
      int p = ((((X << 4) + dx) << 12) + (((Y << 4) + dy) << 6) + ((Z << 4) + dz));
      vs += vs1[p];
      as += as1[p];
    }
    for (int o = 32; o > 0; o >>= 1) {
      vs += __shfl_down(vs, o, 64);
      as += __shfl_down(as, o, 64);
    }
    if (lane == 0) { vs5[w] = vs; as5[w] = as; }
  }
}

// ---------------------------------------------------------------------------
// Scale-0 per-voxel feature write from packed center + 6 packed neighbors.
// Neighbor value 0 (inactive or OOB) -> f=0, m=0.
// ---------------------------------------------------------------------------
__device__ __forceinline__ void s0_write(unsigned pk, const unsigned* n, float* dst) {
  int cc = (int)(pk >> 20);
  float4 r0 = {0.f, 0.f, 0.f, 0.f}, r1 = r0, r2 = r0;
  if (cc) {
    int sc = (int)(pk & 0xFFFFFu);
    float f[6], m[6];
#pragma unroll
    for (int k = 0; k < 6; k++) {
      int cn = (int)(n[k] >> 20);
      int sn = (int)(n[k] & 0xFFFFFu);
      if (cn) {
        long long d = (long long)sn * cc - (long long)sc * cn;
        if (d < 0) d = -d;
        f[k] = (100ll * d < (long long)cn * cc) ? 1.f : 0.f;
        m[k] = 1.f;
      } else {
        f[k] = 0.f;
        m[k] = 0.f;
      }
    }
    r0 = {f[0], f[1], f[2], f[3]};
    r1 = {f[4], f[5], m[0], m[1]};
    r2 = {m[2], m[3], m[4], m[5]};
  }
  float4* o = (float4*)dst;
  o[0] = r0; o[1] = r1; o[2] = r2;
}

// ---------------------------------------------------------------------------
// 4) Fused output kernel. Scale-0: one thread per z-PAIR of voxels (z-neighbor
//    values shared in registers; 96B contiguous stores). Coarse: R14 path.
// ---------------------------------------------------------------------------
__global__ __launch_bounds__(256) void out_kernel(
    const unsigned int* __restrict__ P,
    const double* __restrict__ vs1, const double* __restrict__ as1,
    const double* __restrict__ vs2, const double* __restrict__ as2,
    const double* __restrict__ vs3, const double* __restrict__ as3,
    const double* __restrict__ vs4, const double* __restrict__ as4,
    const double* __restrict__ vs5, const double* __restrict__ as5,
    float* __restrict__ out) {
  int p = blockIdx.x * blockDim.x + threadIdx.x;
  if (p < H0) {
    int pb = p << 1;                       // even-z voxel; pair = {pb, pb+1}
    unsigned pkA = P[pb], pkB = P[pb + 1];
    int x = pb >> 14, y = (pb >> 7) & 127, z = pb & 127;   // z even
    bool xm = x > 0, xp = x < 127, ym = y > 0, yp = y < 127;
    unsigned nA[6], nB[6];
    nA[0] = xm ? P[pb - 16384] : 0u;  nB[0] = xm ? P[pb + 1 - 16384] : 0u;
    nA[1] = xp ? P[pb + 16384] : 0u;  nB[1] = xp ? P[pb + 1 + 16384] : 0u;
    nA[2] = ym ? P[pb - 128] : 0u;    nB[2] = ym ? P[pb + 1 - 128] : 0u;
    nA[3] = yp ? P[pb + 128] : 0u;    nB[3] = yp ? P[pb + 1 + 128] : 0u;
    nA[4] = (z > 0) ? P[pb - 1] : 0u; nB[4] = pkA;
    nA[5] = pkB;                      nB[5] = (z < 126) ? P[pb + 2] : 0u;
    s0_write(pkA, nA, out + 12ll * pb);
    s0_write(pkB, nB, out + 12ll * (pb + 1));
    return;
  }
  int t = p - H0;
  const double *vs, *as;
  int ls, q;
  long long obase;
  if (t < NS1) { q = t; vs = vs1; as = as1; ls = 6; obase = OB1; }
  else if (t < NS1 + NS2) { q = t - NS1; vs = vs2; as = as2; ls = 5; obase = OB2; }
  else if (t < NS1 + NS2 + NS3) { q = t - NS1 - NS2; vs = vs3; as = as3; ls = 4; obase = OB3; }
  else if (t < NS1 + NS2 + NS3 + NS4) { q = t - NS1 - NS2 - NS3; vs = vs4; as = as4; ls = 3; obase = OB4; }
  else if (t < NSALL) { q = t - NS1 - NS2 - NS3 - NS4; vs = vs5; as = as5; ls = 2; obase = OB5; }
  else return;

  int Ss = 1 << ls;
  int X = q >> (2 * ls), Y = (q >> ls) & (Ss - 1), Z = q & (Ss - 1);
  double ac = as[q];
  float4 r0 = {0.f, 0.f, 0.f, 0.f}, r1 = r0, r2 = r0;
  if (ac > 0.0) {
    double vc = vs[q] / ac;
    const int off[6] = {-(Ss * Ss), Ss * Ss, -Ss, Ss, -1, 1};
    const bool inb[6] = {X > 0, X < Ss - 1, Y > 0, Y < Ss - 1, Z > 0, Z < Ss - 1};
    float f[6], m[6];
#pragma unroll
    for (int k = 0; k < 6; k++) {
      double van = 0.0;
      if (inb[k]) {
        double an = as[q + off[k]];
        if (an > 0.0) van = vs[q + off[k]] / an;
      }
      f[k] = (fabs(van - vc) < 0.01) ? 1.f : 0.f;
      m[k] = (van > 0.0) ? 1.f : 0.f;
    }
    r0 = {f[0], f[1], f[2], f[3]};
    r1 = {f[4], f[5], m[0], m[1]};
    r2 = {m[2], m[3], m[4], m[5]};
  }
  float4* o = (float4*)(out + obase + 12ll * q);
  o[0] = r0; o[1] = r1; o[2] = r2;
}

// ---------------------------------------------------------------------------
extern "C" void kernel_launch(void* const* d_in, const int* in_sizes, int n_in,
                              void* d_out, int out_size, void* d_ws, size_t ws_size,
                              hipStream_t stream) {
  const int* coords = (const int*)d_in[0];
  const float* inst = (const float*)d_in[1];
  int N = in_sizes[1];            // 4,000,000 points
  float* out = (float*)d_out;
  int nchunks = (N + PPB - 1) / PPB;                     // 489

  // workspace layout
  char* base = (char*)d_ws;
  unsigned int* P = (unsigned int*)base;                 // 8 MB
  double* vs1 = (double*)(base + 8388608);
  double* as1 = vs1 + NS1;
  double* vs2 = as1 + NS1; double* as2 = vs2 + NS2;
  double* vs3 = as2 + NS2; double* as3 = vs3 + NS3;
  double* vs4 = as3 + NS3; double* as4 = vs4 + NS4;
  double* vs5 = as4 + NS4; double* as5 = vs5 + NS5;     // ends ~13.18 MB
  size_t counts_off = 13182976;                          // 1KB-aligned
  unsigned int* counts = (unsigned int*)(base + counts_off);
  size_t bins_off = counts_off + ((size_t)nchunks * NREG * 4 + 1023) / 1024 * 1024;
  unsigned int* bins = (unsigned int*)(base + bins_off);
  size_t need = bins_off + (size_t)nchunks * NREG * CAPB * 4;  // ~78.4 MB
  if (ws_size < need) return;  // never happens at this problem size

  bin_kernel<<<nchunks, 256, 0, stream>>>(coords, inst, counts, bins, N);
  build_pool_kernel<<<NREG, 256, 0, stream>>>(counts, bins, P, vs1, as1, nchunks);
  poolRest_kernel<<<(NS2 + NS3 + NS4 * 64 + NS5 * 64 + 255) / 256, 256, 0, stream>>>(
      vs1, as1, vs2, as2, vs3, as3, vs4, as4, vs5, as5);
  out_kernel<<<(TEND + 255) / 256, 256, 0, stream>>>(
      P, vs1, as1, vs2, as2, vs3, as3, vs4, as4, vs5, as5, out);
}

// Round 18
// 86.833 us; speedup vs baseline: 1.8305x; 1.0656x over previous
//
#include <hip/hip_runtime.h>

#define GS3 2097152          // 128^3
#define NS1 262144           // 64^3
#define NS2 32768            // 32^3
#define NS3 4096             // 16^3
#define NS4 512              // 8^3
#define NS5 64               // 4^3
#define NSALL 299584         // NS1+NS2+NS3+NS4+NS5

// Output element offsets (float index) for each scale's block of [Ss^3, 12]
#define OB1 25165824
#define OB2 28311552
#define OB3 28704768
#define OB4 28753920
#define OB5 28760064

#define NREG 512             // regions: x-pair (x>>1, 6b) * y-16th (y>>4, 3b)
#define RVOX 4096            // voxels per region: 2(x) * 16(y) * 128(z) = 16KB LDS
#define PPB  8192            // points per binning block
#define RPT  (PPB / 256)     // records per thread (register-staged)
#define CAPB 64              // slot words: [0]=count, [1..63]=records (mean 16, P(>63)~1e-16)

// Record: (region<<18) | (localvoxel<<6) | label
//   region   = (x>>1)<<3 | (y>>4)             (9 bits)
//   localvox = (x&1)<<11 | (y&15)<<7 | z      (12 bits)
//   label    = instance+1                     (6 bits, 1..50)

// ---------------------------------------------------------------------------
// 1a) Binning with block-local counting sort. Raw records in registers;
//     sorted runs + their count written to FIXED per-(block,region) 256B
//     slots (count in word 0) -> no global atomics, fully deterministic,
//     and build reads each slot as ONE contiguous stream.
// ---------------------------------------------------------------------------
__global__ __launch_bounds__(256) void bin_kernel(
    const int* __restrict__ coords, const float* __restrict__ inst,
    unsigned int* __restrict__ bins, int N) {
  __shared__ unsigned srec[PPB];     // 32 KB region-sorted records
  __shared__ unsigned hist[NREG];    // 2 KB: counts, then scatter cursor
  __shared__ unsigned lofs[NREG];    // 2 KB: block-local region starts
  __shared__ unsigned part[256];     // 1 KB: scan workspace
  __shared__ unsigned total_sh;
  unsigned vrec[RPT];                // register-staged raw records
  int tid = threadIdx.x;
  int bid = blockIdx.x;
  int start = bid * PPB;
  for (int j = tid; j < NREG; j += 256) hist[j] = 0;
  __syncthreads();
  // phase 1: read points, build records in registers, count per region
#pragma unroll
  for (int j = 0; j < RPT; j++) {
    int i = start + j * 256 + tid;
    unsigned v = 0xFFFFFFFFu;
    if (i < N) {
      int x = coords[3 * i + 0];
      int y = coords[3 * i + 1];
      int z = coords[3 * i + 2];
      unsigned lab = (unsigned)inst[i] + 1u;                          // 1..50
      unsigned r = (((unsigned)x >> 1) << 3) | ((unsigned)y >> 4);    // 9 bits
      unsigned l = (((unsigned)x & 1) << 11) | (((unsigned)y & 15) << 7) | (unsigned)z;
      v = (r << 18) | (l << 6) | lab;
      atomicAdd(&hist[r], 1u);
    }
    vrec[j] = v;
  }
  __syncthreads();
  // phase 2a: write per-region counts into slot word 0 (clamped), and
  //           exclusive-scan hist[512] -> lofs (2 entries/thread)
  size_t bbase = (size_t)bid * NREG * CAPB;
  unsigned ha = hist[2 * tid], hb = hist[2 * tid + 1];
  bins[bbase + (size_t)(2 * tid) * CAPB]     = ha < CAPB - 1 ? ha : CAPB - 1;
  bins[bbase + (size_t)(2 * tid + 1) * CAPB] = hb < CAPB - 1 ? hb : CAPB - 1;
  part[tid] = ha + hb;
  __syncthreads();
  for (int o = 1; o < 256; o <<= 1) {
    unsigned v = part[tid];
    unsigned add = (tid >= o) ? part[tid - o] : 0u;
    __syncthreads();
    part[tid] = v + add;
    __syncthreads();
  }
  unsigned inc = part[tid];
  unsigned ex = inc - (ha + hb);
  lofs[2 * tid] = ex;
  lofs[2 * tid + 1] = ex + ha;
  if (tid == 255) total_sh = inc;
  __syncthreads();
  for (int j = tid; j < NREG; j += 256) hist[j] = 0;   // reuse as cursor
  __syncthreads();
  // phase 3a: scatter records from registers into region-sorted LDS buffer
#pragma unroll
  for (int j = 0; j < RPT; j++) {
    unsigned v = vrec[j];
    if (v != 0xFFFFFFFFu) {
      unsigned r = v >> 18;
      unsigned pos = lofs[r] + atomicAdd(&hist[r], 1u);
      srec[pos] = v;
    }
  }
  __syncthreads();
  // phase 3b: write sorted runs to slot words [1..63] (coalesced)
  unsigned total = total_sh;
  for (unsigned j = tid; j < total; j += 256) {
    unsigned v = srec[j];
    unsigned r = v >> 18;
    unsigned p = j - lofs[r];                 // position within region run
    if (p < CAPB - 1) bins[bbase + (size_t)r * CAPB + 1 + p] = v & 0x3FFFFu;
  }
}

// ---------------------------------------------------------------------------
// 1b+2) Build P for one region in LDS (gathering the per-block slots, count
//     embedded in slot word 0) and pool its coarse cells (fused pool1).
//     Region r: x in {2X,2X+1} (X=r>>3), y in [yo*16,yo*16+16) (yo=r&7).
// ---------------------------------------------------------------------------
__global__ __launch_bounds__(256) void build_pool_kernel(
    const unsigned int* __restrict__ bins, unsigned int* __restrict__ P,
    double* __restrict__ vs1, double* __restrict__ as1, int nchunks) {
  __shared__ unsigned grid[RVOX];    // 16 KB
  int r = blockIdx.x;
  int tid = threadIdx.x;
  for (int j = tid; j < RVOX; j += 256) grid[j] = 0;
  __syncthreads();
  for (int b = tid; b < nchunks; b += 256) {
    const unsigned* src = bins + ((size_t)b * NREG + r) * CAPB;
    int cb = (int)src[0];
    for (int k = 1; k <= cb; k++) {
      unsigned v = src[k];
      atomicAdd(&grid[v >> 6], (1u << 20) | (v & 63u));
    }
  }
  __syncthreads();
  int X = r >> 3, yo = r & 7;        // x-pair index, y-16th index
  // write P: for each dx, a contiguous 8KB span (16y * 128z dwords)
  unsigned pbase = ((unsigned)(2 * X) << 14) | ((unsigned)yo << 11);
  for (int j = tid; j < RVOX; j += 256) {
    // j = (x&1)<<11 | (y&15)<<7 | z
    P[pbase + ((j >> 11) << 14) + (j & 0x7FF)] = grid[j];
  }
  // fused pool1: 512 coarse cells (1 X-plane, 8 coarse y, 64 coarse z)
  for (int c = tid; c < 512; c += 256) {
    int yl = c >> 6, Z = c & 63;
    double vs = 0.0, as = 0.0;
#pragma unroll
    for (int dx = 0; dx < 2; dx++)
#pragma unroll
      for (int dy = 0; dy < 2; dy++)
#pragma unroll
        for (int dz = 0; dz < 2; dz++) {
          int j = (dx << 11) | ((2 * yl + dy) << 7) | (2 * Z + dz);
          unsigned pk = grid[j];
          unsigned cc = pk >> 20;
          if (cc) {
            vs += (double)(pk & 0xFFFFFu) / (double)cc;
            as += 1.0;
          }
        }
    int q = (X << 12) | (((yo << 3) + yl) << 6) | Z;
    vs1[q] = vs;
    as1[q] = as;
  }
}

// ---------------------------------------------------------------------------
// 3) Pool scales 2..5 from scale-1 sums (sums are additive) — R14-proven.
// ---------------------------------------------------------------------------
__global__ __launch_bounds__(256) void poolRest_kernel(
    const double* __restrict__ vs1, const double* __restrict__ as1,
    double* __restrict__ vs2, double* __restrict__ as2,
    double* __restrict__ vs3, double* __restrict__ as3,
    double* __restrict__ vs4, double* __restrict__ as4,
    double* __restrict__ vs5, double* __restrict__ as5) {
  int t = blockIdx.x * blockDim.x + threadIdx.x;

  if (t < NS2) {
    int q = t;
    int X = q >> 10, Y = (q >> 5) & 31, Z = q & 31;
    double vs = 0.0, as = 0.0;
#pragma unroll
    for (int dx = 0; dx < 2; dx++)
#pragma unroll
      for (int dy = 0; dy < 2; dy++)
#pragma unroll
        for (int dz = 0; dz < 2; dz++) {
          int p = ((((X << 1) + dx) << 12) + (((Y << 1) + dy) << 6) + ((Z << 1) + dz));
          vs += vs1[p];
          as += as1[p];
        }
    vs2[q] = vs;
    as2[q] = as;
    return;
  }
  t -= NS2;
  if (t < NS3) {
    int q = t;
    int X = q >> 8, Y = (q >> 4) & 15, Z = q & 15;
    double vs = 0.0, as = 0.0;
    for (int dx = 0; dx < 4; dx++)
      for (int dy = 0; dy < 4; dy++)
#pragma unroll
        for (int dz = 0; dz < 4; dz++) {
          int p = ((((X << 2) + dx) << 12) + (((Y << 2) + dy) << 6) + ((Z << 2) + dz));
          vs += vs1[p];
          as += as1[p];
        }
    vs3[q] = vs;
    as3[q] = as;
    return;
  }
  t -= NS3;
  if (t < NS4 * 64) {
    int w = t >> 6, lane = t & 63;
    int X = w >> 6, Y = (w >> 3) & 7, Z = w & 7;
    double vs = 0.0, as = 0.0;
#pragma unroll
    for (int j = 0; j < 8; j++) {
      int c = lane * 8 + j;
      int dx = c >> 6, dy = (c >> 3) & 7, dz = c & 7;
      int p = ((((X << 3) + dx) << 12) + (((Y << 3) + dy) << 6) + ((Z << 3) + dz));
      vs += vs1[p];
      as += as1[p];
    }
    for (int o = 32; o > 0; o >>= 1) {
      vs += __shfl_down(vs, o, 64);
      as += __shfl_down(as, o, 64);
    }
    if (lane == 0) { vs4[w] = vs; as4[w] = as; }
    return;
  }
  t -= NS4 * 64;
  if (t < NS5 * 64) {
    int w = t >> 6, lane = t & 63;
    int X = w >> 4, Y = (w >> 2) & 3, Z = w & 3;
    double vs = 0.0, as = 0.0;
    for (int j = 0; j < 64; j++) {
      int c = lane * 64 + j;
      int dx = c >> 8, dy = (c >> 4) & 15, dz = c & 15;
      int p = ((((X << 4) + dx) << 12) + (((Y << 4) + dy) << 6) + ((Z << 4) + dz));
      vs += vs1[p];
      as += as1[p];
    }
    for (int o = 32; o > 0; o >>= 1) {
      vs += __shfl_down(vs, o, 64);
      as += __shfl_down(as, o, 64);
    }
    if (lane == 0) { vs5[w] = vs; as5[w] = as; }
  }
}

// ---------------------------------------------------------------------------
// 4) Fused output kernel (R14-proven: 1 thread/voxel, plain float4 stores).
// ---------------------------------------------------------------------------
__global__ __launch_bounds__(256) void out_kernel(
    const unsigned int* __restrict__ P,
    const double* __restrict__ vs1, const double* __restrict__ as1,
    const double* __restrict__ vs2, const double* __restrict__ as2,
    const double* __restrict__ vs3, const double* __restrict__ as3,
    const double* __restrict__ vs4, const double* __restrict__ as4,
    const double* __restrict__ vs5, const double* __restrict__ as5,
    float* __restrict__ out) {
  int p = blockIdx.x * blockDim.x + threadIdx.x;
  if (p < GS3) {
    unsigned pk = P[p];
    int cc = (int)(pk >> 20);
    float4 r0 = {0.f, 0.f, 0.f, 0.f}, r1 = r0, r2 = r0;
    if (cc) {
      int sc = (int)(pk & 0xFFFFFu);
      int x = p >> 14, y = (p >> 7) & 127, z = p & 127;
      const int off[6] = {-(1 << 14), (1 << 14), -(1 << 7), (1 << 7), -1, 1};
      const bool inb[6] = {x > 0, x < 127, y > 0, y < 127, z > 0, z < 127};
      float f[6], m[6];
#pragma unroll
      for (int k = 0; k < 6; k++) {
        int sn = 0, cn = 0;
        if (inb[k]) {
          unsigned pn = P[p + off[k]];
          cn = (int)(pn >> 20);
          sn = (int)(pn & 0xFFFFFu);
        }
        if (cn) {
          long long d = (long long)sn * cc - (long long)sc * cn;
          if (d < 0) d = -d;
          f[k] = (100ll * d < (long long)cn * cc) ? 1.f : 0.f;
          m[k] = 1.f;
        } else {
          f[k] = 0.f;                          // vc >= 1 so |0-vc| >= 1
          m[k] = 0.f;
        }
      }
      r0 = {f[0], f[1], f[2], f[3]};
      r1 = {f[4], f[5], m[0], m[1]};
      r2 = {m[2], m[3], m[4], m[5]};
    }
    float4* o = (float4*)(out + 12ll * p);
    o[0] = r0; o[1] = r1; o[2] = r2;
    return;
  }
  int t = p - GS3;
  const double *vs, *as;
  int ls, q;
  long long obase;
  if (t < NS1) { q = t; vs = vs1; as = as1; ls = 6; obase = OB1; }
  else if (t < NS1 + NS2) { q = t - NS1; vs = vs2; as = as2; ls = 5; obase = OB2; }
  else if (t < NS1 + NS2 + NS3) { q = t - NS1 - NS2; vs = vs3; as = as3; ls = 4; obase = OB3; }
  else if (t < NS1 + NS2 + NS3 + NS4) { q = t - NS1 - NS2 - NS3; vs = vs4; as = as4; ls = 3; obase = OB4; }
  else if (t < NSALL) { q = t - NS1 - NS2 - NS3 - NS4; vs = vs5; as = as5; ls = 2; obase = OB5; }
  else return;

  int Ss = 1 << ls;
  int X = q >> (2 * ls), Y = (q >> ls) & (Ss - 1), Z = q & (Ss - 1);
  double ac = as[q];
  float4 r0 = {0.f, 0.f, 0.f, 0.f}, r1 = r0, r2 = r0;
  if (ac > 0.0) {
    double vc = vs[q] / ac;
    const int off[6] = {-(Ss * Ss), Ss * Ss, -Ss, Ss, -1, 1};
    const bool inb[6] = {X > 0, X < Ss - 1, Y > 0, Y < Ss - 1, Z > 0, Z < Ss - 1};
    float f[6], m[6];
#pragma unroll
    for (int k = 0; k < 6; k++) {
      double van = 0.0;
      if (inb[k]) {
        double an = as[q + off[k]];
        if (an > 0.0) van = vs[q + off[k]] / an;
      }
      f[k] = (fabs(van - vc) < 0.01) ? 1.f : 0.f;
      m[k] = (van > 0.0) ? 1.f : 0.f;
    }
    r0 = {f[0], f[1], f[2], f[3]};
    r1 = {f[4], f[5], m[0], m[1]};
    r2 = {m[2], m[3], m[4], m[5]};
  }
  float4* o = (float4*)(out + obase + 12ll * q);
  o[0] = r0; o[1] = r1; o[2] = r2;
}

// ---------------------------------------------------------------------------
extern "C" void kernel_launch(void* const* d_in, const int* in_sizes, int n_in,
                              void* d_out, int out_size, void* d_ws, size_t ws_size,
                              hipStream_t stream) {
  const int* coords = (const int*)d_in[0];
  const float* inst = (const float*)d_in[1];
  int N = in_sizes[1];            // 4,000,000 points
  float* out = (float*)d_out;
  int nchunks = (N + PPB - 1) / PPB;                     // 489

  // workspace layout
  char* base = (char*)d_ws;
  unsigned int* P = (unsigned int*)base;                 // 8 MB
  double* vs1 = (double*)(base + 8388608);
  double* as1 = vs1 + NS1;
  double* vs2 = as1 + NS1; double* as2 = vs2 + NS2;
  double* vs3 = as2 + NS2; double* as3 = vs3 + NS3;
  double* vs4 = as3 + NS3; double* as4 = vs4 + NS4;
  double* vs5 = as4 + NS4; double* as5 = vs5 + NS5;     // ends ~13.18 MB
  size_t bins_off = 13182976;                            // 1KB-aligned
  unsigned int* bins = (unsigned int*)(base + bins_off);
  size_t need = bins_off + (size_t)nchunks * NREG * CAPB * 4;  // ~77.3 MB
  if (ws_size < need) return;  // never happens at this problem size

  bin_kernel<<<nchunks, 256, 0, stream>>>(coords, inst, bins, N);
  build_pool_kernel<<<NREG, 256, 0, stream>>>(bins, P, vs1, as1, nchunks);
  poolRest_kernel<<<(NS2 + NS3 + NS4 * 64 + NS5 * 64 + 255) / 256, 256, 0, stream>>>(
      vs1, as1, vs2, as2, vs3, as3, vs4, as4, vs5, as5);
  out_kernel<<<(GS3 + NSALL + 255) / 256, 256, 0, stream>>>(
      P, vs1, as1, vs2, as2, vs3, as3, vs4, as4, vs5, as5, out);
}